// Round 1
// baseline (1441.430 us; speedup 1.0000x reference)
//
#include <hip/hip_runtime.h>
#include <hip/hip_bf16.h>

#define T_TOK 8192
#define DDIM 1024
#define HDIM 4096

typedef __bf16 bf16;
typedef bf16 bf16x8 __attribute__((ext_vector_type(8)));
typedef float f32x4 __attribute__((ext_vector_type(4)));

__device__ __forceinline__ void gl_lds16(const void* g, void* l) {
  __builtin_amdgcn_global_load_lds(
      (const __attribute__((address_space(1))) unsigned int*)g,
      (__attribute__((address_space(3))) unsigned int*)l, 16, 0, 0);
}

// ---------------- x fp32 -> bf16 ----------------
__global__ __launch_bounds__(256) void convert_x(const float* __restrict__ x,
                                                 bf16* __restrict__ xb) {
  const size_t i = ((size_t)blockIdx.x * 256 + threadIdx.x) * 8;
  const float4 v0 = *(const float4*)(x + i);
  const float4 v1 = *(const float4*)(x + i + 4);
  bf16x8 o;
  o[0] = (bf16)v0.x; o[1] = (bf16)v0.y; o[2] = (bf16)v0.z; o[3] = (bf16)v0.w;
  o[4] = (bf16)v1.x; o[5] = (bf16)v1.y; o[6] = (bf16)v1.z; o[7] = (bf16)v1.w;
  *(bf16x8*)(xb + i) = o;
}

// ---------------- weight transpose + convert: src [R,C] f32 -> dst [C,R] bf16
__global__ __launch_bounds__(256) void transpose_convert(
    const float* __restrict__ src, bf16* __restrict__ dst, int R, int C) {
  __shared__ float tile[32][33];
  const size_t mat = (size_t)blockIdx.z * R * C;
  const int c0 = blockIdx.x * 32, r0 = blockIdx.y * 32;
  const int tx = threadIdx.x & 31, ty = threadIdx.x >> 5;  // 32 x 8
#pragma unroll
  for (int i = 0; i < 4; ++i)
    tile[ty + 8 * i][tx] =
        src[mat + (size_t)(r0 + ty + 8 * i) * C + c0 + tx];
  __syncthreads();
#pragma unroll
  for (int i = 0; i < 4; ++i)
    dst[mat + (size_t)(c0 + ty + 8 * i) * R + r0 + tx] =
        (bf16)tile[tx][ty + 8 * i];
}

// ---------------- router: softmax/top2/gates + aux sums ----------------
__global__ __launch_bounds__(256) void router_kernel(
    const float* __restrict__ x, const float* __restrict__ srw,
    const float* __restrict__ srb, const float* __restrict__ hrw,
    const float* __restrict__ hrb, float* __restrict__ gate,
    float* __restrict__ auxg) {
  __shared__ float saux[8];
  if (threadIdx.x < 8) saux[threadIdx.x] = 0.0f;
  __syncthreads();

  const int lane = threadIdx.x & 63;
  const int w = threadIdx.x >> 6;
  const int t = blockIdx.x * 4 + w;

  const float* xr = x + (size_t)t * DDIM;
  float p0 = 0, p1 = 0, p2 = 0, p3 = 0, p4 = 0, p5 = 0;
#pragma unroll
  for (int c = 0; c < 4; ++c) {
    const int d = c * 256 + lane * 4;
    const float4 xv = *(const float4*)(xr + d);
    const float xa[4] = {xv.x, xv.y, xv.z, xv.w};
#pragma unroll
    for (int j = 0; j < 4; ++j) {
      const float xd = xa[j];
      const float4 r4 = *(const float4*)(srw + (size_t)(d + j) * 4);
      p0 += xd * r4.x; p1 += xd * r4.y; p2 += xd * r4.z; p3 += xd * r4.w;
      const float2 r2 = *(const float2*)(hrw + (size_t)(d + j) * 2);
      p4 += xd * r2.x; p5 += xd * r2.y;
    }
  }
#pragma unroll
  for (int off = 32; off >= 1; off >>= 1) {
    p0 += __shfl_xor(p0, off);
    p1 += __shfl_xor(p1, off);
    p2 += __shfl_xor(p2, off);
    p3 += __shfl_xor(p3, off);
    p4 += __shfl_xor(p4, off);
    p5 += __shfl_xor(p5, off);
  }
  if (lane == 0) {
    const float l0 = p0 + srb[0], l1 = p1 + srb[1];
    const float l2 = p2 + srb[2], l3 = p3 + srb[3];
    const float m = fmaxf(fmaxf(l0, l1), fmaxf(l2, l3));
    const float e0 = expf(l0 - m), e1 = expf(l1 - m);
    const float e2 = expf(l2 - m), e3 = expf(l3 - m);
    const float s = e0 + e1 + e2 + e3;
    float pr[4] = {e0 / s, e1 / s, e2 / s, e3 / s};
    int i1 = 0; float v1 = pr[0];
#pragma unroll
    for (int e = 1; e < 4; ++e) if (pr[e] > v1) { v1 = pr[e]; i1 = e; }
    int i2 = -1; float v2 = -1.0f;
#pragma unroll
    for (int e = 0; e < 4; ++e)
      if (e != i1 && pr[e] > v2) { v2 = pr[e]; i2 = e; }
    float g[4] = {0, 0, 0, 0};
    g[i1] = v1; g[i2] = v2;
    float* gr = gate + (size_t)t * 8;
    gr[0] = g[0]; gr[1] = g[1]; gr[2] = g[2]; gr[3] = g[3];
    const float h0 = p4 + hrb[0], h1 = p5 + hrb[1];
    const float mh = fmaxf(h0, h1);
    const float q0 = expf(h0 - mh), q1 = expf(h1 - mh);
    const float qs = q0 + q1;
    gr[4] = q0 / qs; gr[5] = q1 / qs; gr[6] = 0; gr[7] = 0;
    atomicAdd(&saux[i1], 1.0f);
    atomicAdd(&saux[i2], 1.0f);
    atomicAdd(&saux[4 + 0], pr[0]);
    atomicAdd(&saux[4 + 1], pr[1]);
    atomicAdd(&saux[4 + 2], pr[2]);
    atomicAdd(&saux[4 + 3], pr[3]);
  }
  __syncthreads();
  if (threadIdx.x < 8) atomicAdd(&auxg[threadIdx.x], saux[threadIdx.x]);
}

__global__ void init_aux(float* auxg) {
  if (threadIdx.x < 8) auxg[threadIdx.x] = 0.0f;
}

__global__ void aux_finalize(const float* __restrict__ auxg,
                             float* __restrict__ outp) {
  float a = 0.0f;
#pragma unroll
  for (int e = 0; e < 4; ++e)
    a += (auxg[e] / (float)(T_TOK * 2)) * (auxg[4 + e] / (float)T_TOK);
  outp[0] = 4.0f * a;
}

// ---------------- GEMM C = A[M,K] * B[N,K]^T  (both bf16, B pre-transposed)
// MODE 0: Hout = gelu(C + bias)  (bf16)
// MODE 1: Fout += gate[:,gidx] * (C + bias)
// MODE 2: Fout  = gate[:,gidx] * (C + bias)
#define BM 128
#define BN 128
#define BK 32

template <int MODE>
__global__ __launch_bounds__(256) void gemm_bt(
    const bf16* __restrict__ A, const bf16* __restrict__ B, int M, int N,
    int K, const float* __restrict__ bias, bf16* __restrict__ Hout,
    float* __restrict__ Fout, const float* __restrict__ gate, int gidx) {
  __shared__ bf16 Alds[BM * BK];
  __shared__ bf16 Blds[BN * BK];

  const int tid = threadIdx.x;
  const int lane = tid & 63;
  const int wid = tid >> 6;
  const int wm = wid >> 1;
  const int wn = wid & 1;
  const int lr = lane & 15;
  const int lg = lane >> 4;
  const int bm = blockIdx.x, bn = blockIdx.y;

  const int srow = tid >> 2;         // 0..63
  const int scol = (tid & 3) * 8;    // 0,8,16,24

  const bf16* Ag = A + (size_t)(bm * BM + srow) * K + scol;
  const bf16* Bg = B + (size_t)(bn * BN + srow) * K + scol;
  bf16* Al = Alds + wid * 512;  // wave-uniform LDS base (byte = wid*1024)
  bf16* Bl = Blds + wid * 512;

  f32x4 acc[4][4] = {};

  for (int k0 = 0; k0 < K; k0 += BK) {
    gl_lds16(Ag + k0, Al);
    gl_lds16(Ag + (size_t)64 * K + k0, Al + 2048);
    gl_lds16(Bg + k0, Bl);
    gl_lds16(Bg + (size_t)64 * K + k0, Bl + 2048);
    __syncthreads();

    bf16x8 a[4], b[4];
#pragma unroll
    for (int mf = 0; mf < 4; ++mf)
      a[mf] = *(const bf16x8*)&Alds[(wm * 64 + mf * 16 + lr) * BK + lg * 8];
#pragma unroll
    for (int nf = 0; nf < 4; ++nf)
      b[nf] = *(const bf16x8*)&Blds[(wn * 64 + nf * 16 + lr) * BK + lg * 8];
#pragma unroll
    for (int mf = 0; mf < 4; ++mf)
#pragma unroll
      for (int nf = 0; nf < 4; ++nf)
        acc[mf][nf] = __builtin_amdgcn_mfma_f32_16x16x32_bf16(
            a[mf], b[nf], acc[mf][nf], 0, 0, 0);
    __syncthreads();
  }

#pragma unroll
  for (int mf = 0; mf < 4; ++mf) {
#pragma unroll
    for (int nf = 0; nf < 4; ++nf) {
      const int col = bn * BN + wn * 64 + nf * 16 + lr;
      const float bv = bias[col];
#pragma unroll
      for (int r = 0; r < 4; ++r) {
        const int row = bm * BM + wm * 64 + mf * 16 + lg * 4 + r;
        const float v = acc[mf][nf][r] + bv;
        if (MODE == 0) {
          const float gl = 0.5f * v * (1.0f + erff(v * 0.7071067811865475f));
          Hout[(size_t)row * N + col] = (bf16)gl;
        } else {
          const float gv = gate[(size_t)row * 8 + gidx];
          const size_t oi = (size_t)row * N + col;
          if (MODE == 1)
            Fout[oi] += gv * v;
          else
            Fout[oi] = gv * v;
        }
      }
    }
  }
}

extern "C" void kernel_launch(void* const* d_in, const int* in_sizes, int n_in,
                              void* d_out, int out_size, void* d_ws,
                              size_t ws_size, hipStream_t stream) {
  const float* x = (const float*)d_in[0];
  const float* spec_w1 = (const float*)d_in[1];
  const float* spec_b1 = (const float*)d_in[2];
  const float* spec_w2 = (const float*)d_in[3];
  const float* spec_b2 = (const float*)d_in[4];
  const float* spec_rw = (const float*)d_in[5];
  const float* spec_rb = (const float*)d_in[6];
  const float* shr_w1 = (const float*)d_in[7];
  const float* shr_b1 = (const float*)d_in[8];
  const float* shr_w2 = (const float*)d_in[9];
  const float* shr_b2 = (const float*)d_in[10];
  const float* shr_rw = (const float*)d_in[11];
  const float* shr_rb = (const float*)d_in[12];
  float* out = (float*)d_out;

  char* ws = (char*)d_ws;
  const size_t SZ_X = (size_t)T_TOK * DDIM * 2;           // 16,777,216
  const size_t SZ_W = (size_t)6 * DDIM * HDIM * 2;        // 50,331,648
  bf16* xb = (bf16*)ws;
  bf16* w1t = (bf16*)(ws + SZ_X);
  bf16* w2t = (bf16*)(ws + SZ_X + SZ_W);
  bf16* hbuf = (bf16*)(ws + SZ_X + 2 * SZ_W);
  float* gate = (float*)(ws + SZ_X + 2 * SZ_W + (size_t)T_TOK * HDIM * 2);
  float* auxg = gate + (size_t)T_TOK * 8;

  init_aux<<<1, 64, 0, stream>>>(auxg);
  convert_x<<<(T_TOK * DDIM) / 2048, 256, 0, stream>>>(x, xb);
  transpose_convert<<<dim3(HDIM / 32, DDIM / 32, 4), 256, 0, stream>>>(
      spec_w1, w1t, DDIM, HDIM);
  transpose_convert<<<dim3(HDIM / 32, DDIM / 32, 2), 256, 0, stream>>>(
      shr_w1, w1t + (size_t)4 * DDIM * HDIM, DDIM, HDIM);
  transpose_convert<<<dim3(DDIM / 32, HDIM / 32, 4), 256, 0, stream>>>(
      spec_w2, w2t, HDIM, DDIM);
  transpose_convert<<<dim3(DDIM / 32, HDIM / 32, 2), 256, 0, stream>>>(
      shr_w2, w2t + (size_t)4 * DDIM * HDIM, HDIM, DDIM);
  router_kernel<<<T_TOK / 4, 256, 0, stream>>>(x, spec_rw, spec_rb, shr_rw,
                                               shr_rb, gate, auxg);

  for (int e = 0; e < 6; ++e) {
    const bf16* w1e = w1t + (size_t)e * DDIM * HDIM;
    const bf16* w2e = w2t + (size_t)e * DDIM * HDIM;
    const float* b1e =
        (e < 4) ? spec_b1 + (size_t)e * HDIM : shr_b1 + (size_t)(e - 4) * HDIM;
    const float* b2e =
        (e < 4) ? spec_b2 + (size_t)e * DDIM : shr_b2 + (size_t)(e - 4) * DDIM;
    const int gidx = e;  // gate layout: 0..3 spec, 4..5 shared

    gemm_bt<0><<<dim3(T_TOK / BM, HDIM / BN), 256, 0, stream>>>(
        xb, w1e, T_TOK, HDIM, DDIM, b1e, hbuf, nullptr, nullptr, 0);
    if (e == 0)
      gemm_bt<2><<<dim3(T_TOK / BM, DDIM / BN), 256, 0, stream>>>(
          hbuf, w2e, T_TOK, DDIM, HDIM, b2e, nullptr, out, gate, gidx);
    else
      gemm_bt<1><<<dim3(T_TOK / BM, DDIM / BN), 256, 0, stream>>>(
          hbuf, w2e, T_TOK, DDIM, HDIM, b2e, nullptr, out, gate, gidx);
  }
  aux_finalize<<<1, 1, 0, stream>>>(auxg, out + (size_t)T_TOK * DDIM);
}